// Round 1
// baseline (530.881 us; speedup 1.0000x reference)
//
#include <hip/hip_runtime.h>

// NeuralSpectralBlock1d on MI355X (gfx950)
// B=32, C=256, H=4096, PATCH=4, HEAD=8, DH=32, NT=4, NB=12
// Fused design:
//   wconv_kernel: enc_w(512x256) ++ dec_w(256x256) -> bf16 Wb[768][256] in d_ws
//   nsb_kernel:   grid 2048 = 32 b * 64 col-chunks; block 512 thr (8 waves)
//     phase 1: Y(768x64) = Wb @ X(256x64) via mfma_f32_16x16x32_bf16
//              wave w owns rows [w*96, w*96+96): acc[6][4] f32x4 (96 VGPRs)
//     phase 2: two halves of 32 cols (8 patches); wave <-> patch:
//              E/D LDS overlay -> attn1 -> spectral (sin/cos + Chebyshev
//              recurrence) -> attn2 -> +xp -> scrambled unpatchify store
//
// LDS map (59904 B total, <= 64 KB static limit):
//   GEMM:   A [0,55296)      768 rows * 72 B (32 bf16 + pad; 2-way-free reads)
//           Bx [55296,59904)  64 rows * 72 B
//   epilog: E  [0,32896)     32 cols * 1028 B; (k,v) pair word, d+4h swizzle
//           D  [0,16896)     32 cols * 528 B  (written after attn1; E is dead)
//           LT [32896,50304) 8 patches * 4 l * 544 B
//           QL [50304,54528) latent fp32, [h][l][33] padded

typedef __attribute__((ext_vector_type(8))) short short8;
typedef __attribute__((ext_vector_type(4))) float f32x4;

#define BOFF 55296
#define DOFF 0
#define LTOFF 32896
#define QLOFF 50304

__device__ __forceinline__ unsigned short f2bf(float f) {
  union { float f; unsigned int u; } c; c.f = f;
  unsigned int u = c.u + 0x7FFFu + ((c.u >> 16) & 1u);
  return (unsigned short)(u >> 16);
}
__device__ __forceinline__ float bf2f(unsigned short s) {
  union { unsigned int u; float f; } c; c.u = ((unsigned int)s) << 16;
  return c.f;
}

__global__ void wconv_kernel(const float* __restrict__ enc_w,
                             const float* __restrict__ dec_w,
                             unsigned short* __restrict__ Wb) {
  int i4 = (blockIdx.x * 256 + threadIdx.x) * 4;  // grid 192*256*4 = 196608 exact
  float4 v;
  if (i4 < 131072) v = *(const float4*)(enc_w + i4);
  else             v = *(const float4*)(dec_w + (i4 - 131072));
  ushort4 o;
  o.x = f2bf(v.x); o.y = f2bf(v.y); o.z = f2bf(v.z); o.w = f2bf(v.w);
  *(ushort4*)(Wb + i4) = o;
}

__global__ __launch_bounds__(512) void nsb_kernel(
    const float* __restrict__ x,
    const float* __restrict__ weights,
    const float* __restrict__ latent,
    const float* __restrict__ enc_b,
    const float* __restrict__ dec_b,
    const unsigned short* __restrict__ Wb,
    float* __restrict__ out)
{
  __shared__ __attribute__((aligned(16))) unsigned char smem[59904];
  const int t    = threadIdx.x;
  const int wv   = t >> 6;       // wave 0..7
  const int lane = t & 63;
  const int fm   = lane & 15;    // mfma m/n index
  const int quad = lane >> 4;    // mfma k-group / row-quad
  const int bb   = blockIdx.x >> 6;          // batch
  const int h0   = (blockIdx.x & 63) << 6;   // column base in H

  f32x4 acc[6][4];
#pragma unroll
  for (int i = 0; i < 6; ++i)
#pragma unroll
    for (int j = 0; j < 4; ++j)
      acc[i][j] = f32x4{0.f, 0.f, 0.f, 0.f};

  // ---------------- phase 1: GEMM Y = W @ X ----------------
  const int arow = t >> 2, akq = t & 3;        // A staging: 128 rows x 4 kq per round
  const int bk = t >> 4, bn4 = (t & 15) << 2;  // B staging: 32 k x 16 n4

  for (int kt = 0; kt < 8; ++kt) {
    const int k0 = kt << 5;
#pragma unroll
    for (int rd = 0; rd < 6; ++rd) {
      const int row = rd * 128 + arow;
      const uint4 w4 = *(const uint4*)(Wb + row * 256 + k0 + akq * 8);
      unsigned char* dst = smem + row * 72 + akq * 16;
      *(uint2*)(dst)     = make_uint2(w4.x, w4.y);
      *(uint2*)(dst + 8) = make_uint2(w4.z, w4.w);
    }
    {
      const float4 xv = *(const float4*)(x + (bb * 256 + k0 + bk) * 4096 + h0 + bn4);
      unsigned char* bp = smem + BOFF + bk * 2;  // transpose-scatter (b16 x4)
      *(unsigned short*)(bp + (bn4 + 0) * 72) = f2bf(xv.x);
      *(unsigned short*)(bp + (bn4 + 1) * 72) = f2bf(xv.y);
      *(unsigned short*)(bp + (bn4 + 2) * 72) = f2bf(xv.z);
      *(unsigned short*)(bp + (bn4 + 3) * 72) = f2bf(xv.w);
    }
    __syncthreads();
    short8 bfrag[4];
#pragma unroll
    for (int j = 0; j < 4; ++j) {
      const unsigned char* p = smem + BOFF + (j * 16 + fm) * 72 + quad * 16;
      union { short8 s; uint2 u[2]; } tb;
      tb.u[0] = *(const uint2*)(p);
      tb.u[1] = *(const uint2*)(p + 8);
      bfrag[j] = tb.s;
    }
#pragma unroll
    for (int i = 0; i < 6; ++i) {
      const unsigned char* p = smem + (wv * 96 + i * 16 + fm) * 72 + quad * 16;
      union { short8 s; uint2 u[2]; } ta;
      ta.u[0] = *(const uint2*)(p);
      ta.u[1] = *(const uint2*)(p + 8);
#pragma unroll
      for (int j = 0; j < 4; ++j)
        acc[i][j] = __builtin_amdgcn_mfma_f32_16x16x32_bf16(ta.s, bfrag[j], acc[i][j], 0, 0, 0);
    }
    __syncthreads();
  }

  // ---------------- epilogue setup ----------------
  float biasr[6][4];
#pragma unroll
  for (int i = 0; i < 6; ++i)
#pragma unroll
    for (int r = 0; r < 4; ++r) {
      const int row = wv * 96 + i * 16 + quad * 4 + r;
      biasr[i][r] = (row < 512) ? enc_b[row] : dec_b[row - 512];
    }
  {
    const int e0 = t * 2;
    const float2 lv = *(const float2*)(latent + e0);
    int h_ = e0 >> 7, l_ = (e0 >> 5) & 3, d_ = e0 & 31;
    *(float*)(smem + QLOFF + (h_ * 132 + l_ * 33 + d_) * 4) = lv.x;
    const int e1 = e0 + 1;
    h_ = e1 >> 7; l_ = (e1 >> 5) & 3; d_ = e1 & 31;
    *(float*)(smem + QLOFF + (h_ * 132 + l_ * 33 + d_) * 4) = lv.y;
  }
  __syncthreads();

#pragma unroll
  for (int hf = 0; hf < 2; ++hf) {
    // ---- write E (enc rows, +bias), bf16 (k,v) pair-packed, swizzled ----
#pragma unroll
    for (int i = 0; i < 6; ++i) {
      const int row0 = wv * 96 + i * 16 + quad * 4;
      if (row0 < 512) {
#pragma unroll
        for (int jj = 0; jj < 2; ++jj) {
#pragma unroll
          for (int r = 0; r < 4; ++r) {
            const int row = row0 + r;
            const int col = jj * 16 + fm;  // 0..31 within half
            const float v = acc[i][hf * 2 + jj][r] + biasr[i][r];
            const int h_ = row >> 6, rem = row & 63;
            const int d_ = rem >> 1, kvb = rem & 1;
            const int word = col * 257 + h_ * 32 + ((d_ + 4 * h_) & 31);
            *(unsigned short*)(smem + word * 4 + kvb * 2) = f2bf(v);
          }
        }
      }
    }
    __syncthreads();

    // ---- attention 1: wave <-> patch, lanes 0..31 = (h, l) ----
    if (lane < 32) {
      const int hh = lane >> 2, ll = lane & 3;
      const unsigned int* Ew = (const unsigned int*)smem;
      const float* QLb = (const float*)(smem + QLOFF) + hh * 132 + ll * 33;
      const int cb = wv * 4;
      float s0 = 0.f, s1 = 0.f, s2 = 0.f, s3 = 0.f;
      for (int d = 0; d < 32; ++d) {
        const float qd = QLb[d];
        const int wb_ = hh * 32 + ((d + 4 * hh) & 31);
        const unsigned int kv0 = Ew[(cb + 0) * 257 + wb_];
        const unsigned int kv1 = Ew[(cb + 1) * 257 + wb_];
        const unsigned int kv2 = Ew[(cb + 2) * 257 + wb_];
        const unsigned int kv3 = Ew[(cb + 3) * 257 + wb_];
        s0 += qd * bf2f((unsigned short)kv0);
        s1 += qd * bf2f((unsigned short)kv1);
        s2 += qd * bf2f((unsigned short)kv2);
        s3 += qd * bf2f((unsigned short)kv3);
      }
      const float mx = fmaxf(fmaxf(s0, s1), fmaxf(s2, s3));
      const float e0 = __expf(s0 - mx), e1 = __expf(s1 - mx);
      const float e2 = __expf(s2 - mx), e3 = __expf(s3 - mx);
      const float inv = 1.f / (e0 + e1 + e2 + e3);
      const float a0 = e0 * inv, a1 = e1 * inv, a2_ = e2 * inv, a3 = e3 * inv;
      unsigned char* LTb = smem + LTOFF + wv * 2176 + ll * 544 + hh * 64;
      for (int d2 = 0; d2 < 16; ++d2) {
        unsigned int pk = 0;
#pragma unroll
        for (int dd = 0; dd < 2; ++dd) {
          const int d = d2 * 2 + dd;
          const float qd = QLb[d];
          const int wb_ = hh * 32 + ((d + 4 * hh) & 31);
          const unsigned int kv0 = Ew[(cb + 0) * 257 + wb_];
          const unsigned int kv1 = Ew[(cb + 1) * 257 + wb_];
          const unsigned int kv2 = Ew[(cb + 2) * 257 + wb_];
          const unsigned int kv3 = Ew[(cb + 3) * 257 + wb_];
          const float lv = qd + a0 * bf2f((unsigned short)(kv0 >> 16))
                              + a1 * bf2f((unsigned short)(kv1 >> 16))
                              + a2_ * bf2f((unsigned short)(kv2 >> 16))
                              + a3 * bf2f((unsigned short)(kv3 >> 16));
          pk |= ((unsigned int)f2bf(lv)) << (16 * dd);
        }
        *(unsigned int*)(LTb + d2 * 4) = pk;
      }
    }
    __syncthreads();

    // ---- write D (dec rows, +bias) into E's dead space ----
#pragma unroll
    for (int i = 0; i < 6; ++i) {
      const int row0 = wv * 96 + i * 16 + quad * 4;
      if (row0 >= 512) {
#pragma unroll
        for (int jj = 0; jj < 2; ++jj) {
#pragma unroll
          for (int r = 0; r < 4; ++r) {
            const int row = row0 + r;
            const int col = jj * 16 + fm;
            const float v = acc[i][hf * 2 + jj][r] + biasr[i][r];
            *(unsigned short*)(smem + DOFF + col * 528 + (row - 512) * 2) = f2bf(v);
          }
        }
      }
    }
    // ---- spectral: in-place on LT; sin/cos once + angle-addition recurrence ----
    {
      unsigned char* LTp = smem + LTOFF + wv * 2176;
#pragma unroll
      for (int ii = 0; ii < 4; ++ii) {
        const int ic = ii * 64 + lane;  // channel i in [0,256)
        const float* wrp = weights + ic * 24;
        float wr_[24];
#pragma unroll
        for (int q2 = 0; q2 < 6; ++q2) {
          const float4 wq = *(const float4*)(wrp + q2 * 4);
          wr_[q2 * 4 + 0] = wq.x; wr_[q2 * 4 + 1] = wq.y;
          wr_[q2 * 4 + 2] = wq.z; wr_[q2 * 4 + 3] = wq.w;
        }
#pragma unroll
        for (int l2 = 0; l2 < 4; ++l2) {
          unsigned short* ps = (unsigned short*)(LTp + l2 * 544 + ic * 2);
          const float val = bf2f(*ps);
          const float th = val * 0.26179938779914946f;  // pi/12
          const float sn = __sinf(th), cs = __cosf(th);
          float av = wr_[12];  // m=0: cos term only
          float sm = sn, cm = cs;
#pragma unroll
          for (int mq = 1; mq <= 11; ++mq) {
            av += wr_[mq] * sm + wr_[12 + mq] * cm;
            if (mq < 11) {
              const float ns = sm * cs + cm * sn;
              cm = cm * cs - sm * sn;
              sm = ns;
            }
          }
          *ps = f2bf(av + val);
        }
      }
    }
    __syncthreads();

    // ---- attention 2 + xp + store: lanes 0..31 = (h, pp) ----
    if (lane < 32) {
      const int hh = lane >> 2, pp = lane & 3;
      const int col = wv * 4 + pp;
      const unsigned char* Db  = smem + DOFF + col * 528 + hh * 64;
      const unsigned char* LTp = smem + LTOFF + wv * 2176;
      float dq[32];
#pragma unroll
      for (int c8 = 0; c8 < 4; ++c8) {
        union { uint2 u[2]; unsigned short us[8]; } td;
        td.u[0] = *(const uint2*)(Db + c8 * 16);
        td.u[1] = *(const uint2*)(Db + c8 * 16 + 8);
#pragma unroll
        for (int e = 0; e < 8; ++e) dq[c8 * 8 + e] = bf2f(td.us[e]);
      }
      float sc2[4];
#pragma unroll
      for (int l2 = 0; l2 < 4; ++l2) {
        float sa = 0.f;
#pragma unroll
        for (int c8 = 0; c8 < 4; ++c8) {
          union { uint2 u[2]; unsigned short us[8]; } tl;
          const unsigned char* p = LTp + l2 * 544 + hh * 64 + c8 * 16;
          tl.u[0] = *(const uint2*)(p);
          tl.u[1] = *(const uint2*)(p + 8);
#pragma unroll
          for (int e = 0; e < 8; ++e) sa += dq[c8 * 8 + e] * bf2f(tl.us[e]);
        }
        sc2[l2] = sa;
      }
      const float mx2 = fmaxf(fmaxf(sc2[0], sc2[1]), fmaxf(sc2[2], sc2[3]));
      float ex[4];
#pragma unroll
      for (int l2 = 0; l2 < 4; ++l2) ex[l2] = __expf(sc2[l2] - mx2);
      const float inv2 = 1.f / (ex[0] + ex[1] + ex[2] + ex[3]);
      float aw[4];
#pragma unroll
      for (int l2 = 0; l2 < 4; ++l2) aw[l2] = ex[l2] * inv2;

      const int hpf = (blockIdx.x & 63) * 16 + hf * 8 + wv;  // Hp index
      const int hg  = h0 + hf * 32 + wv * 4 + pp;            // h index
      float* ob = out + bb * 1048576 + pp * 262144 + hpf * 256 + hh * 32;
      const float* xc = x + bb * 1048576 + (hh * 32) * 4096 + hg;
#pragma unroll
      for (int c8 = 0; c8 < 4; ++c8) {
        float ov[8];
#pragma unroll
        for (int e = 0; e < 8; ++e) ov[e] = 0.f;
#pragma unroll
        for (int l2 = 0; l2 < 4; ++l2) {
          union { uint2 u[2]; unsigned short us[8]; } tl;
          const unsigned char* p = LTp + l2 * 544 + hh * 64 + c8 * 16;
          tl.u[0] = *(const uint2*)(p);
          tl.u[1] = *(const uint2*)(p + 8);
#pragma unroll
          for (int e = 0; e < 8; ++e) ov[e] += aw[l2] * bf2f(tl.us[e]);
        }
#pragma unroll
        for (int e = 0; e < 8; ++e) ov[e] += xc[(c8 * 8 + e) * 4096];
        *(float4*)(ob + c8 * 8)     = make_float4(ov[0], ov[1], ov[2], ov[3]);
        *(float4*)(ob + c8 * 8 + 4) = make_float4(ov[4], ov[5], ov[6], ov[7]);
      }
    }
    __syncthreads();
  }
}

extern "C" void kernel_launch(void* const* d_in, const int* in_sizes, int n_in,
                              void* d_out, int out_size, void* d_ws, size_t ws_size,
                              hipStream_t stream) {
  const float* x       = (const float*)d_in[0];
  const float* weights = (const float*)d_in[1];
  const float* latent  = (const float*)d_in[2];
  const float* enc_w   = (const float*)d_in[3];
  const float* enc_b   = (const float*)d_in[4];
  const float* dec_w   = (const float*)d_in[5];
  const float* dec_b   = (const float*)d_in[6];
  unsigned short* Wb   = (unsigned short*)d_ws;  // 768*256 bf16 = 384 KB
  float* outp          = (float*)d_out;

  wconv_kernel<<<192, 256, 0, stream>>>(enc_w, dec_w, Wb);
  nsb_kernel<<<2048, 512, 0, stream>>>(x, weights, latent, enc_b, dec_b, Wb, outp);
}